// Round 18
// baseline (2236.997 us; speedup 1.0000x reference)
//
// ============================================================================
// Round 18: optimization of the passing R17 pipeline (fp32 in/out, dict order).
//  - Full-size Q/K GEMMs (256 blocks), no phase-B recompute, no final copy.
//  - jacobi_eig: 64-thread single-wave blocks (cheap barriers), NSWEEP 6.
//  - Scratch: Wq buf (G/W2/musum/hw/Dval, then V b2,b3) ; Wk buf (V b0,b1);
//    hs (ctx x4 after last hs read); out-GEMMs write d_out directly.
// ============================================================================
#include <hip/hip_runtime.h>
#include <hip/hip_bf16.h>

typedef __attribute__((ext_vector_type(8))) short v8s;
typedef __attribute__((ext_vector_type(4))) float v4f;
typedef __hip_bfloat16 bf16;

#define NSWEEP 6

__device__ __forceinline__ float bf2f(short s) {
    unsigned int u = ((unsigned int)(unsigned short)s) << 16;
    return __uint_as_float(u);
}

__global__ void diag_f32(float* __restrict__ out, size_t n, float code)
{
    for (size_t i = (size_t)blockIdx.x * 256 + threadIdx.x; i < n;
         i += (size_t)gridDim.x * 256)
        out[i] = (i == 0) ? code : 0.0f;
}

// ---------------------------------------------------------------------------
// half_omega[d] = 0.5 * sum_m (sum_j rm[d][j]*on[m][j])^2   (fp32, np pairwise)
// ---------------------------------------------------------------------------
__global__ __launch_bounds__(64)
void half_omega_k(const float* __restrict__ rm, const float* __restrict__ on,
                  float* __restrict__ hw)
{
    __shared__ float ons[64][64];
    int t = threadIdx.x;
    for (int r = 0; r < 64; ++r) ons[r][t] = on[r * 64 + t];
    __syncthreads();
    float rmv[64];
#pragma unroll
    for (int j = 0; j < 64; ++j) rmv[j] = rm[t * 64 + j];
    float r8[8];
#pragma unroll
    for (int i = 0; i < 8; ++i) r8[i] = 0.0f;
    for (int k = 0; k < 8; ++k) {
#pragma unroll
        for (int i = 0; i < 8; ++i) {
            int m = k * 8 + i;
            float dot = 0.0f;
#pragma unroll
            for (int j = 0; j < 64; ++j) dot += rmv[j] * ons[m][j];
            r8[i] += dot * dot;
        }
    }
    float acc = ((r8[0] + r8[1]) + (r8[2] + r8[3])) + ((r8[4] + r8[5]) + (r8[6] + r8[7]));
    hw[t] = 0.5f * acc;
}

// ---------------------------------------------------------------------------
// GEMM (A @ W^T + bias) * scale.  W,bias fp32.
// MODE 1: A fp32 [M][1024]; out bf16 [bh][s][d] (bh = m>>10 within launch).
// MODE 3: A bf16 ctx local [h][s][d] (16 heads); out fp32 [s][n].
// ---------------------------------------------------------------------------
template<int MODE>
__global__ __launch_bounds__(256)
void gemm_nt(const void* __restrict__ Ap, const float* __restrict__ W,
             const float* __restrict__ bias, float scale,
             bf16* __restrict__ outB, float* __restrict__ outF)
{
    const int K = 1024;
    __shared__ bf16 As[128][40];
    __shared__ bf16 Bs[128][40];
    int t = threadIdx.x;
    int m0 = blockIdx.x * 128;
    int n0 = blockIdx.y * 128;
    int lane = t & 63, w = t >> 6;
    int wm = (w >> 1) * 64, wn = (w & 1) * 64;
    int l15 = lane & 15, quad = lane >> 4;

    v4f zz = {0.f, 0.f, 0.f, 0.f};
    v4f acc[4][4];
#pragma unroll
    for (int i = 0; i < 4; ++i)
#pragma unroll
        for (int j = 0; j < 4; ++j) acc[i][j] = zz;

    for (int k0 = 0; k0 < K; k0 += 32) {
        __syncthreads();
        if (MODE == 1) {
            const float* A = (const float*)Ap;
#pragma unroll
            for (int r2 = 0; r2 < 4; ++r2) {
                int idx = t + r2 * 256;
                int row = idx >> 3, kc = (idx & 7) * 4;
                float4 v = *(const float4*)&A[(size_t)(m0 + row) * K + k0 + kc];
                As[row][kc + 0] = __float2bfloat16(v.x);
                As[row][kc + 1] = __float2bfloat16(v.y);
                As[row][kc + 2] = __float2bfloat16(v.z);
                As[row][kc + 3] = __float2bfloat16(v.w);
            }
        } else {
            const bf16* A = (const bf16*)Ap;
#pragma unroll
            for (int r2 = 0; r2 < 2; ++r2) {
                int idx = t + r2 * 256;
                int row = idx >> 2, kc = (idx & 3) * 8;
                int kk = k0 + kc;
                int h = kk >> 6, d = kk & 63;
                *(float4*)&As[row][kc] =
                    *(const float4*)&A[((size_t)h * 1024 + m0 + row) * 64 + d];
            }
        }
#pragma unroll
        for (int r2 = 0; r2 < 4; ++r2) {
            int idx = t + r2 * 256;
            int row = idx >> 3, kc = (idx & 7) * 4;
            float4 v = *(const float4*)&W[(size_t)(n0 + row) * K + k0 + kc];
            Bs[row][kc + 0] = __float2bfloat16(v.x);
            Bs[row][kc + 1] = __float2bfloat16(v.y);
            Bs[row][kc + 2] = __float2bfloat16(v.z);
            Bs[row][kc + 3] = __float2bfloat16(v.w);
        }
        __syncthreads();
        v8s af[4], bfr[4];
#pragma unroll
        for (int i = 0; i < 4; ++i)
            af[i] = *(v8s*)&As[wm + i * 16 + l15][quad * 8];
#pragma unroll
        for (int j = 0; j < 4; ++j)
            bfr[j] = *(v8s*)&Bs[wn + j * 16 + l15][quad * 8];
#pragma unroll
        for (int i = 0; i < 4; ++i)
#pragma unroll
            for (int j = 0; j < 4; ++j)
                acc[i][j] = __builtin_amdgcn_mfma_f32_16x16x32_bf16(af[i], bfr[j], acc[i][j], 0, 0, 0);
    }
#pragma unroll
    for (int i = 0; i < 4; ++i)
#pragma unroll
        for (int j = 0; j < 4; ++j)
#pragma unroll
            for (int r = 0; r < 4; ++r) {
                int m = m0 + wm + i * 16 + quad * 4 + r;
                int n = n0 + wn + j * 16 + l15;
                float val = (acc[i][j][r] + bias[n]) * scale;
                if (MODE == 1) {
                    int b = m >> 10, s = m & 1023, h = n >> 6, d = n & 63;
                    outB[(((size_t)(b * 16 + h) * 1024 + s) << 6) + d] = __float2bfloat16(val);
                } else {
                    outF[(size_t)m * 1024 + n] = val;
                }
            }
}

// ---------------------------------------------------------------------------
// Gram + mean statistics, all 64 bh (grid 64 x 16)
// ---------------------------------------------------------------------------
__global__ __launch_bounds__(256)
void gram_stats(const bf16* __restrict__ qb, const bf16* __restrict__ kb,
                float* __restrict__ G, float* __restrict__ musum)
{
    __shared__ float qt[64][68];
    __shared__ float ktl[64][68];
    int bh = blockIdx.x, sc = blockIdx.y;
    int t = threadIdx.x;
    size_t base = ((size_t)bh * 1024 + sc * 64) * 64;
#pragma unroll
    for (int r = 0; r < 2; ++r) {
        int c = t + r * 256;
        int row = c >> 3, c8 = (c & 7) * 8;
        v8s vq = *(const v8s*)&qb[base + row * 64 + c8];
        v8s vk = *(const v8s*)&kb[base + row * 64 + c8];
#pragma unroll
        for (int i = 0; i < 8; ++i) {
            qt[row][c8 + i] = bf2f(vq[i]);
            ktl[row][c8 + i] = bf2f(vk[i]);
        }
    }
    __syncthreads();
    int tj = t & 15, ti = t >> 4;
    float aq[4][4], ak[4][4];
#pragma unroll
    for (int r = 0; r < 4; ++r)
#pragma unroll
        for (int c = 0; c < 4; ++c) { aq[r][c] = 0.f; ak[r][c] = 0.f; }
    for (int s = 0; s < 64; ++s) {
        float qd[4], qe[4], kd[4], ke[4];
#pragma unroll
        for (int r = 0; r < 4; ++r) {
            qd[r] = qt[s][ti * 4 + r]; qe[r] = qt[s][tj * 4 + r];
            kd[r] = ktl[s][ti * 4 + r]; ke[r] = ktl[s][tj * 4 + r];
        }
#pragma unroll
        for (int r = 0; r < 4; ++r)
#pragma unroll
            for (int c = 0; c < 4; ++c) {
                aq[r][c] += qd[r] * qe[c];
                ak[r][c] += kd[r] * ke[c];
            }
    }
    float* Gp = G + (size_t)bh * 4096;
#pragma unroll
    for (int r = 0; r < 4; ++r)
#pragma unroll
        for (int c = 0; c < 4; ++c)
            atomicAdd(&Gp[(ti * 4 + r) * 64 + tj * 4 + c], aq[r][c] + ak[r][c]);
    if (t < 128) {
        int which = t >> 6, d = t & 63;
        float s0 = 0.0f;
        if (which == 0) { for (int s = 0; s < 64; ++s) s0 += qt[s][d]; }
        else            { for (int s = 0; s < 64; ++s) s0 += ktl[s][d]; }
        atomicAdd(&musum[((size_t)which * 64 + bh) * 64 + d], s0);
    }
}

// ---------------------------------------------------------------------------
// per-bh 64x64 Jacobi eig — SINGLE WAVE (64 threads): barriers are intra-wave
// and nearly free.  W2 aliases G (staged to LDS first).
// ---------------------------------------------------------------------------
__global__ __launch_bounds__(64)
void jacobi_eig(const float* __restrict__ G, const float* __restrict__ musum,
                float* __restrict__ W2, float* __restrict__ Dval)
{
    __shared__ float Ab[2][64][65];
    __shared__ float Vb[2][64][65];
    __shared__ float ca[64], sb[64];
    __shared__ float lam[64];
    __shared__ float muqs[64], muks[64];
    int bh = blockIdx.x, t = threadIdx.x;
    const float invS = 1.0f / 1024.0f;
    muqs[t] = musum[(size_t)bh * 64 + t] * invS;
    muks[t] = musum[4096 + (size_t)bh * 64 + t] * invS;
    __syncthreads();
    const float* Gb = G + (size_t)bh * 4096;
    for (int r = 0; r < 64; ++r) {
        Ab[0][r][t] = Gb[r * 64 + t] * invS + muqs[r] * muks[t] + muks[r] * muqs[t];
        Vb[0][r][t] = (r == t) ? 1.0f : 0.0f;
    }
    __syncthreads();
    int cur = 0;
    for (int sweep = 0; sweep < NSWEEP; ++sweep) {
        for (int m = 1; m < 64; ++m) {
            int q = t ^ m;
            if (t < q) {
                float app = Ab[cur][t][t], aqq = Ab[cur][q][q], apq = Ab[cur][t][q];
                float c = 1.0f, s = 0.0f;
                if (fabsf(apq) > 1e-28f) {
                    double tau = (double)(aqq - app) / (2.0 * (double)apq);
                    double tt = (tau >= 0.0 ? 1.0 : -1.0) / (fabs(tau) + sqrt(1.0 + tau * tau));
                    double cd = 1.0 / sqrt(1.0 + tt * tt);
                    c = (float)cd; s = (float)(tt * cd);
                }
                ca[t] = c; sb[t] = -s;
                ca[q] = c; sb[q] = s;
            }
            __syncthreads();
            int nxt = cur ^ 1;
            int hb = 31 - __builtin_clz((unsigned)m);
            int lowmask = (1 << hb) - 1;
#pragma unroll 4
            for (int r = 0; r < 16; ++r) {
                int idx = t + r * 64;
                int ki = idx >> 5, kj = idx & 31;
                int i1 = ((ki & ~lowmask) << 1) | (ki & lowmask);
                int i2 = i1 ^ m;
                int j1 = ((kj & ~lowmask) << 1) | (kj & lowmask);
                int j2 = j1 ^ m;
                float a11 = Ab[cur][i1][j1], a12 = Ab[cur][i1][j2];
                float a21 = Ab[cur][i2][j1], a22 = Ab[cur][i2][j2];
                float ci = ca[i1], si = sb[i1], ci2 = ca[i2], si2 = sb[i2];
                float cj = ca[j1], sj = sb[j1], cj2 = ca[j2], sj2 = sb[j2];
                float t11 = ci * a11 + si * a21, t12 = ci * a12 + si * a22;
                float t21 = ci2 * a21 + si2 * a11, t22 = ci2 * a22 + si2 * a12;
                Ab[nxt][i1][j1] = cj * t11 + sj * t12;
                Ab[nxt][i1][j2] = cj2 * t12 + sj2 * t11;
                Ab[nxt][i2][j1] = cj * t21 + sj * t22;
                Ab[nxt][i2][j2] = cj2 * t22 + sj2 * t21;
            }
#pragma unroll 4
            for (int r = 0; r < 32; ++r) {
                int idx = t + r * 64;
                int i = idx >> 5, kj = idx & 31;
                int j1 = ((kj & ~lowmask) << 1) | (kj & lowmask);
                int j2 = j1 ^ m;
                float v1 = Vb[cur][i][j1], v2 = Vb[cur][i][j2];
                Vb[nxt][i][j1] = ca[j1] * v1 + sb[j1] * v2;
                Vb[nxt][i][j2] = ca[j2] * v2 + sb[j2] * v1;
            }
            cur = nxt;
            __syncthreads();
        }
    }
    lam[t] = Ab[cur][t][t];
    __syncthreads();
    {
        int j = t;
        float lj = lam[j];
        int rank = 0;
        for (int k2 = 0; k2 < 64; ++k2) {
            float lk = lam[k2];
            rank += (lk > lj) || (lk == lj && k2 < j);
        }
        float tl = 2.0f * lj + 1.0f;
        float om = (3.0f + 2.0f * lj + sqrtf(tl * tl + 8.0f * lj)) * 0.25f;
        float cfac = sqrtf(om);
        float best = -1.0f; int bd = 0;
        for (int d = 0; d < 64; ++d) {
            float av = fabsf(Vb[cur][d][j]);
            if (av > best) { best = av; bd = d; }
        }
        if (Vb[cur][bd][j] < 0.0f) cfac = -cfac;
        for (int d = 0; d < 64; ++d)
            W2[((size_t)bh * 64 + d) * 64 + rank] = cfac * Vb[cur][d][j];
        ca[j] = logf(om);
    }
    __syncthreads();
    if (t == 0) {
        float ssum = 0.0f;
        for (int j = 0; j < 64; ++j) ssum += ca[j];
        Dval[bh] = expf(0.25f * ssum);
    }
}

// ---------------------------------------------------------------------------
// feature map IN PLACE, all 64 bh (grid 64 x 16 x 2); overflow -> inf -> 0
// ---------------------------------------------------------------------------
__global__ __launch_bounds__(64)
void features_k(bf16* __restrict__ qb, bf16* __restrict__ kb,
                const float* __restrict__ W2g, const float* __restrict__ Dv,
                const float* __restrict__ hw)
{
    __shared__ float Wsh[64][64];
    __shared__ float hD[64];
    int bh = blockIdx.x, st = blockIdx.y, qk = blockIdx.z;
    int t = threadIdx.x;
    const float* W2b = W2g + (size_t)bh * 4096;
#pragma unroll
    for (int r = 0; r < 16; ++r)
        ((float4*)Wsh)[t + r * 64] = ((const float4*)W2b)[t + r * 64];
    hD[t] = hw[t] + Dv[t];
    bf16* buf = qk ? kb : qb;
    int row = st * 64 + t;
    bf16* rowp = buf + ((size_t)bh * 1024 + row) * 64;
    float q[64];
#pragma unroll
    for (int c = 0; c < 8; ++c) {
        v8s v = *(const v8s*)&rowp[c * 8];
#pragma unroll
        for (int i = 0; i < 8; ++i) q[c * 8 + i] = bf2f(v[i]);
    }
    __syncthreads();
    float x[64];
#pragma unroll
    for (int e = 0; e < 64; ++e) x[e] = hD[e];
    for (int d = 0; d < 64; ++d) {
        float qd = q[d];
        const float4* wrow = (const float4*)&Wsh[d][0];
#pragma unroll
        for (int e4 = 0; e4 < 16; ++e4) {
            float4 wv = wrow[e4];
            x[e4 * 4 + 0] += qd * wv.x;
            x[e4 * 4 + 1] += qd * wv.y;
            x[e4 * 4 + 2] += qd * wv.z;
            x[e4 * 4 + 3] += qd * wv.w;
        }
    }
    float te[64];
#pragma unroll
    for (int e = 0; e < 64; ++e) te[e] = expf(x[e]);
    float r8[8];
#pragma unroll
    for (int i = 0; i < 8; ++i) r8[i] = te[i] * te[i];
#pragma unroll
    for (int k = 1; k < 8; ++k)
#pragma unroll
        for (int i = 0; i < 8; ++i) r8[i] += te[k * 8 + i] * te[k * 8 + i];
    float s2 = ((r8[0] + r8[1]) + (r8[2] + r8[3])) + ((r8[4] + r8[5]) + (r8[6] + r8[7]));
    float inv = 1.0f / sqrtf(s2);     // inf -> 0 (np semantics)
#pragma unroll
    for (int e2 = 0; e2 < 32; ++e2) {
        __hip_bfloat162 pr;
        pr.x = __float2bfloat16(te[2 * e2] * inv);
        pr.y = __float2bfloat16(te[2 * e2 + 1] * inv);
        *(__hip_bfloat162*)&rowp[2 * e2] = pr;
    }
}

// ---------------------------------------------------------------------------
// flash attention for one batch (16 local heads); ctx -> bf16 local [h][s][d]
// ---------------------------------------------------------------------------
__global__ __launch_bounds__(256)
void flash_attn(const bf16* __restrict__ qn, const bf16* __restrict__ kn,
                const bf16* __restrict__ vv, bf16* __restrict__ ctx)
{
    __shared__ bf16 kt_s[64][72];
    __shared__ bf16 vt_s[64][72];
    __shared__ bf16 p_s[4][16][72];
    int bhl = blockIdx.x, qt = blockIdx.y;
    int t = threadIdx.x, lane = t & 63, w = t >> 6;
    int quad = lane >> 4, l15 = lane & 15;

    int qrow = qt * 64 + w * 16 + l15;
    const bf16* qptr = qn + ((size_t)bhl * 1024 + qrow) * 64;
    v8s aq0 = *(const v8s*)&qptr[quad * 8];
    v8s aq1 = *(const v8s*)&qptr[32 + quad * 8];

    v4f zz = {0.f, 0.f, 0.f, 0.f};
    v4f ctxa[4];
#pragma unroll
    for (int dj = 0; dj < 4; ++dj) ctxa[dj] = zz;
    float mrun[4], lrun[4];
#pragma unroll
    for (int r = 0; r < 4; ++r) { mrun[r] = -__builtin_inff(); lrun[r] = 0.0f; }

    for (int kt = 0; kt < 16; ++kt) {
        __syncthreads();
#pragma unroll
        for (int r2 = 0; r2 < 2; ++r2) {
            int idx = t + r2 * 256;
            int row = idx >> 3, c8 = (idx & 7) * 8;
            size_t goff = ((size_t)bhl * 1024 + kt * 64 + row) * 64 + c8;
            *(float4*)&kt_s[row][c8] = *(const float4*)&kn[goff];
            v8s vchunk = *(const v8s*)&vv[goff];
#pragma unroll
            for (int i = 0; i < 8; ++i)
                ((short*)vt_s)[(c8 + i) * 72 + row] = vchunk[i];
        }
        __syncthreads();
        v4f sa[4];
#pragma unroll
        for (int j = 0; j < 4; ++j) {
            v8s bk0 = *(v8s*)&kt_s[j * 16 + l15][quad * 8];
            v8s bk1 = *(v8s*)&kt_s[j * 16 + l15][32 + quad * 8];
            v4f z = zz;
            z = __builtin_amdgcn_mfma_f32_16x16x32_bf16(aq0, bk0, z, 0, 0, 0);
            sa[j] = __builtin_amdgcn_mfma_f32_16x16x32_bf16(aq1, bk1, z, 0, 0, 0);
        }
        float pv[4][4];
        float alpha[4];
#pragma unroll
        for (int r = 0; r < 4; ++r) {
            float mx = fmaxf(fmaxf(sa[0][r], sa[1][r]), fmaxf(sa[2][r], sa[3][r]));
#pragma unroll
            for (int off = 1; off < 16; off <<= 1) mx = fmaxf(mx, __shfl_xor(mx, off, 64));
            float mnew = fmaxf(mrun[r], mx);
            alpha[r] = __expf(mrun[r] - mnew);
            float ps = 0.0f;
#pragma unroll
            for (int j = 0; j < 4; ++j) {
                float pe = __expf(sa[j][r] - mnew);
                pv[j][r] = pe; ps += pe;
            }
#pragma unroll
            for (int off = 1; off < 16; off <<= 1) ps += __shfl_xor(ps, off, 64);
            mrun[r] = mnew;
            lrun[r] = lrun[r] * alpha[r] + ps;
        }
#pragma unroll
        for (int j = 0; j < 4; ++j)
#pragma unroll
            for (int r = 0; r < 4; ++r)
                p_s[w][quad * 4 + r][j * 16 + l15] = __float2bfloat16(pv[j][r]);
#pragma unroll
        for (int dj = 0; dj < 4; ++dj)
#pragma unroll
            for (int r = 0; r < 4; ++r) ctxa[dj][r] *= alpha[r];
        __syncthreads();
        v8s ap0 = *(v8s*)&p_s[w][l15][quad * 8];
        v8s ap1 = *(v8s*)&p_s[w][l15][32 + quad * 8];
#pragma unroll
        for (int dj = 0; dj < 4; ++dj) {
            v8s bv0 = *(v8s*)&vt_s[dj * 16 + l15][quad * 8];
            v8s bv1 = *(v8s*)&vt_s[dj * 16 + l15][32 + quad * 8];
            ctxa[dj] = __builtin_amdgcn_mfma_f32_16x16x32_bf16(ap0, bv0, ctxa[dj], 0, 0, 0);
            ctxa[dj] = __builtin_amdgcn_mfma_f32_16x16x32_bf16(ap1, bv1, ctxa[dj], 0, 0, 0);
        }
    }
#pragma unroll
    for (int dj = 0; dj < 4; ++dj)
#pragma unroll
        for (int r = 0; r < 4; ++r) {
            int srow = qt * 64 + w * 16 + quad * 4 + r;
            int d = dj * 16 + l15;
            float val = ctxa[dj][r] / lrun[r];
            ctx[((size_t)bhl * 1024 + srow) * 64 + d] = __float2bfloat16(val);
        }
}

// ---------------------------------------------------------------------------
extern "C" void kernel_launch(void* const* d_in, const int* in_sizes, int n_in,
                              void* d_out, int out_size, void* d_ws, size_t ws_size,
                              hipStream_t stream)
{
    const size_t OUT_N = 4194304;
    // ratio-based layout detection (unit-agnostic)
    long mx = 0; int ih = -1;
    for (int i = 0; i < n_in; ++i)
        if ((long)in_sizes[i] > mx) { mx = in_sizes[i]; ih = i; }
    long szW = mx / 4, szR = mx / 1024, szB = mx / 4096;
    int wI[4], rI[2], bI[4], nW = 0, nR = 0, nB = 0;
    bool bad = (n_in != 11) || (mx % 4096 != 0);
    if (!bad) {
        for (int i = 0; i < n_in; ++i) {
            if (i == ih) continue;
            long s = in_sizes[i];
            if (s == szW && nW < 4) wI[nW++] = i;
            else if (s == szR && nR < 2) rI[nR++] = i;
            else if (s == szB && nB < 4) bI[nB++] = i;
            else bad = true;
        }
        if (nW != 4 || nR != 2 || nB != 4) bad = true;
    }
    if (bad) {
        diag_f32<<<256, 256, 0, stream>>>((float*)d_out, OUT_N, 333.0f);
        return;
    }
    const float *Wq, *Wk, *Wv, *Wo, *bq, *bk, *bv, *bo, *rm, *on;
    float *WqS, *WkS;         // writable views of the dead weight buffers
    if (ih == 8 && wI[0] == 0 && wI[1] == 1 && wI[2] == 2 && wI[3] == 3) {
        // sorted keys: Wk,Wo,Wq,Wv,bk,bo,bq,bv,hs,on,rm
        Wk = (const float*)d_in[wI[0]]; Wo = (const float*)d_in[wI[1]];
        Wq = (const float*)d_in[wI[2]]; Wv = (const float*)d_in[wI[3]];
        bk = (const float*)d_in[bI[0]]; bo = (const float*)d_in[bI[1]];
        bq = (const float*)d_in[bI[2]]; bv = (const float*)d_in[bI[3]];
        on = (const float*)d_in[rI[0]]; rm = (const float*)d_in[rI[1]];
        WqS = (float*)d_in[wI[2]]; WkS = (float*)d_in[wI[0]];
    } else {
        // dict/signature: W,b in q,k,v,o order; rm before on
        Wq = (const float*)d_in[wI[0]]; Wk = (const float*)d_in[wI[1]];
        Wv = (const float*)d_in[wI[2]]; Wo = (const float*)d_in[wI[3]];
        bq = (const float*)d_in[bI[0]]; bk = (const float*)d_in[bI[1]];
        bv = (const float*)d_in[bI[2]]; bo = (const float*)d_in[bI[3]];
        rm = (const float*)d_in[rI[0]]; on = (const float*)d_in[rI[1]];
        WqS = (float*)d_in[wI[0]]; WkS = (float*)d_in[wI[1]];
    }
    const float* hs = (const float*)d_in[ih];
    float* outF = (float*)d_out;

    // arenas
    bf16* Qf = (bf16*)d_out;                       // [0,8MB): Q all bh
    bf16* Kf = (bf16*)((char*)d_out + (8u << 20)); // [8MB,16MB): K all bh
    float* G     = WqS;                            // 1MB (G, then W2 in place)
    float* musum = WqS + 262144;                   // +1MB (32KB)
    float* hw    = WqS + 262144 + 16384;           // +1MB+64KB
    float* Dval  = WqS + 262144 + 16384 + 1024;
    // V slots (bf16, 1M elements each): Wk buf halves, then Wq buf halves
    bf16* Vs[4] = { (bf16*)WkS, (bf16*)WkS + 1048576,
                    (bf16*)WqS, (bf16*)WqS + 1048576 };
    // ctx slots in hs (dead after V-GEMMs)
    bf16* Cs[4] = { (bf16*)d_in[ih], (bf16*)d_in[ih] + 1048576,
                    (bf16*)d_in[ih] + 2097152, (bf16*)d_in[ih] + 3145728 };

    const float scale = 0.125f;                    // 1/sqrt(64)
    // 1-2: full Q/K GEMMs (Wq/Wk become dead scratch afterwards)
    gemm_nt<1><<<dim3(32, 8), 256, 0, stream>>>(hs, Wq, bq, scale, Qf, nullptr);
    gemm_nt<1><<<dim3(32, 8), 256, 0, stream>>>(hs, Wk, bk, scale, Kf, nullptr);
    // 3: stats buffers inside dead Wq
    hipMemsetAsync(G, 0, 1u << 20, stream);
    hipMemsetAsync(musum, 0, 32768, stream);
    half_omega_k<<<1, 64, 0, stream>>>(rm, on, hw);
    // 4-5: gram + eig
    gram_stats<<<dim3(64, 16), 256, 0, stream>>>(Qf, Kf, G, musum);
    jacobi_eig<<<64, 64, 0, stream>>>(G, musum, G, Dval);
    // 6: features in place on Q/K (W2, hw, Dval dead afterwards)
    features_k<<<dim3(64, 16, 2), 64, 0, stream>>>(Qf, Kf, G, Dval, hw);
    // 7: V per batch into dead weight buffers (last reads of hs)
    for (int b = 0; b < 4; ++b)
        gemm_nt<1><<<dim3(8, 8), 256, 0, stream>>>(hs + (size_t)b * 1048576, Wv, bv,
                                                   1.0f, Vs[b], nullptr);
    // 8: flash per batch, ctx into dead hs
    for (int b = 0; b < 4; ++b)
        flash_attn<<<dim3(16, 16), 256, 0, stream>>>(Qf + (size_t)b * 1048576,
                                                     Kf + (size_t)b * 1048576,
                                                     Vs[b], Cs[b]);
    // 9: output projection straight into d_out (Q/K dead after flash)
    for (int b = 0; b < 4; ++b)
        gemm_nt<3><<<dim3(8, 8), 256, 0, stream>>>(Cs[b], Wo, bo, 1.0f, nullptr,
                                                   outF + (size_t)b * 1048576);
}

// Round 19
// 840.631 us; speedup vs baseline: 2.6611x; 2.6611x over previous
//
// ============================================================================
// Round 19: jacobi back to multi-wave (512 thr, fp32 c/s, in-place A/V),
// merged V/flash/out launches.  Structure otherwise = R18 (fp32 in/out, dict).
// ============================================================================
#include <hip/hip_runtime.h>
#include <hip/hip_bf16.h>

typedef __attribute__((ext_vector_type(8))) short v8s;
typedef __attribute__((ext_vector_type(4))) float v4f;
typedef __hip_bfloat16 bf16;

#define NSWEEP 6

__device__ __forceinline__ float bf2f(short s) {
    unsigned int u = ((unsigned int)(unsigned short)s) << 16;
    return __uint_as_float(u);
}

__global__ void diag_f32(float* __restrict__ out, size_t n, float code)
{
    for (size_t i = (size_t)blockIdx.x * 256 + threadIdx.x; i < n;
         i += (size_t)gridDim.x * 256)
        out[i] = (i == 0) ? code : 0.0f;
}

// ---------------------------------------------------------------------------
__global__ __launch_bounds__(64)
void half_omega_k(const float* __restrict__ rm, const float* __restrict__ on,
                  float* __restrict__ hw)
{
    __shared__ float ons[64][64];
    int t = threadIdx.x;
    for (int r = 0; r < 64; ++r) ons[r][t] = on[r * 64 + t];
    __syncthreads();
    float rmv[64];
#pragma unroll
    for (int j = 0; j < 64; ++j) rmv[j] = rm[t * 64 + j];
    float r8[8];
#pragma unroll
    for (int i = 0; i < 8; ++i) r8[i] = 0.0f;
    for (int k = 0; k < 8; ++k) {
#pragma unroll
        for (int i = 0; i < 8; ++i) {
            int m = k * 8 + i;
            float dot = 0.0f;
#pragma unroll
            for (int j = 0; j < 64; ++j) dot += rmv[j] * ons[m][j];
            r8[i] += dot * dot;
        }
    }
    float acc = ((r8[0] + r8[1]) + (r8[2] + r8[3])) + ((r8[4] + r8[5]) + (r8[6] + r8[7]));
    hw[t] = 0.5f * acc;
}

// ---------------------------------------------------------------------------
// GEMM (A @ W^T + bias) * scale.  W,bias fp32, K=1024.
// MODE 1: A fp32 [M][1024] -> out bf16 global [bh][s][d]   (Q/K, M=4096)
// MODE 2: A fp32 [4096][1024] -> V slots o0..o3, local [h][s][d] per slot
// MODE 3: A bf16 global [bh][s][d] -> out fp32 [m][n]      (final proj)
// ---------------------------------------------------------------------------
template<int MODE>
__global__ __launch_bounds__(256)
void gemm_nt(const void* __restrict__ Ap, const float* __restrict__ W,
             const float* __restrict__ bias, float scale,
             bf16* __restrict__ o0, bf16* __restrict__ o1,
             bf16* __restrict__ o2, bf16* __restrict__ o3,
             float* __restrict__ outF)
{
    const int K = 1024;
    __shared__ bf16 As[128][40];
    __shared__ bf16 Bs[128][40];
    int t = threadIdx.x;
    int m0 = blockIdx.x * 128;
    int n0 = blockIdx.y * 128;
    int lane = t & 63, w = t >> 6;
    int wm = (w >> 1) * 64, wn = (w & 1) * 64;
    int l15 = lane & 15, quad = lane >> 4;

    v4f zz = {0.f, 0.f, 0.f, 0.f};
    v4f acc[4][4];
#pragma unroll
    for (int i = 0; i < 4; ++i)
#pragma unroll
        for (int j = 0; j < 4; ++j) acc[i][j] = zz;

    for (int k0 = 0; k0 < K; k0 += 32) {
        __syncthreads();
        if (MODE != 3) {
            const float* A = (const float*)Ap;
#pragma unroll
            for (int r2 = 0; r2 < 4; ++r2) {
                int idx = t + r2 * 256;
                int row = idx >> 3, kc = (idx & 7) * 4;
                float4 v = *(const float4*)&A[(size_t)(m0 + row) * K + k0 + kc];
                As[row][kc + 0] = __float2bfloat16(v.x);
                As[row][kc + 1] = __float2bfloat16(v.y);
                As[row][kc + 2] = __float2bfloat16(v.z);
                As[row][kc + 3] = __float2bfloat16(v.w);
            }
        } else {
            const bf16* A = (const bf16*)Ap;
#pragma unroll
            for (int r2 = 0; r2 < 2; ++r2) {
                int idx = t + r2 * 256;
                int row = idx >> 2, kc = (idx & 3) * 8;
                int kk = k0 + kc;
                int h = kk >> 6, d = kk & 63;
                int mr = m0 + row;
                int b = mr >> 10, s = mr & 1023;
                *(float4*)&As[row][kc] =
                    *(const float4*)&A[(((size_t)(b * 16 + h) * 1024 + s) << 6) + d];
            }
        }
#pragma unroll
        for (int r2 = 0; r2 < 4; ++r2) {
            int idx = t + r2 * 256;
            int row = idx >> 3, kc = (idx & 7) * 4;
            float4 v = *(const float4*)&W[(size_t)(n0 + row) * K + k0 + kc];
            Bs[row][kc + 0] = __float2bfloat16(v.x);
            Bs[row][kc + 1] = __float2bfloat16(v.y);
            Bs[row][kc + 2] = __float2bfloat16(v.z);
            Bs[row][kc + 3] = __float2bfloat16(v.w);
        }
        __syncthreads();
        v8s af[4], bfr[4];
#pragma unroll
        for (int i = 0; i < 4; ++i)
            af[i] = *(v8s*)&As[wm + i * 16 + l15][quad * 8];
#pragma unroll
        for (int j = 0; j < 4; ++j)
            bfr[j] = *(v8s*)&Bs[wn + j * 16 + l15][quad * 8];
#pragma unroll
        for (int i = 0; i < 4; ++i)
#pragma unroll
            for (int j = 0; j < 4; ++j)
                acc[i][j] = __builtin_amdgcn_mfma_f32_16x16x32_bf16(af[i], bfr[j], acc[i][j], 0, 0, 0);
    }
    bf16* vout = nullptr;
    if (MODE == 2) {
        int b = m0 >> 10;
        vout = (b == 0) ? o0 : (b == 1) ? o1 : (b == 2) ? o2 : o3;
    }
#pragma unroll
    for (int i = 0; i < 4; ++i)
#pragma unroll
        for (int j = 0; j < 4; ++j)
#pragma unroll
            for (int r = 0; r < 4; ++r) {
                int m = m0 + wm + i * 16 + quad * 4 + r;
                int n = n0 + wn + j * 16 + l15;
                float val = (acc[i][j][r] + bias[n]) * scale;
                if (MODE == 1) {
                    int b = m >> 10, s = m & 1023, h = n >> 6, d = n & 63;
                    o0[(((size_t)(b * 16 + h) * 1024 + s) << 6) + d] = __float2bfloat16(val);
                } else if (MODE == 2) {
                    int s = m & 1023, h = n >> 6, d = n & 63;
                    vout[(((size_t)h * 1024 + s) << 6) + d] = __float2bfloat16(val);
                } else {
                    outF[(size_t)m * 1024 + n] = val;
                }
            }
}

// ---------------------------------------------------------------------------
// Gram + mean statistics, all 64 bh (grid 64 x 16)
// ---------------------------------------------------------------------------
__global__ __launch_bounds__(256)
void gram_stats(const bf16* __restrict__ qb, const bf16* __restrict__ kb,
                float* __restrict__ G, float* __restrict__ musum)
{
    __shared__ float qt[64][68];
    __shared__ float ktl[64][68];
    int bh = blockIdx.x, sc = blockIdx.y;
    int t = threadIdx.x;
    size_t base = ((size_t)bh * 1024 + sc * 64) * 64;
#pragma unroll
    for (int r = 0; r < 2; ++r) {
        int c = t + r * 256;
        int row = c >> 3, c8 = (c & 7) * 8;
        v8s vq = *(const v8s*)&qb[base + row * 64 + c8];
        v8s vk = *(const v8s*)&kb[base + row * 64 + c8];
#pragma unroll
        for (int i = 0; i < 8; ++i) {
            qt[row][c8 + i] = bf2f(vq[i]);
            ktl[row][c8 + i] = bf2f(vk[i]);
        }
    }
    __syncthreads();
    int tj = t & 15, ti = t >> 4;
    float aq[4][4], ak[4][4];
#pragma unroll
    for (int r = 0; r < 4; ++r)
#pragma unroll
        for (int c = 0; c < 4; ++c) { aq[r][c] = 0.f; ak[r][c] = 0.f; }
    for (int s = 0; s < 64; ++s) {
        float qd[4], qe[4], kd[4], ke[4];
#pragma unroll
        for (int r = 0; r < 4; ++r) {
            qd[r] = qt[s][ti * 4 + r]; qe[r] = qt[s][tj * 4 + r];
            kd[r] = ktl[s][ti * 4 + r]; ke[r] = ktl[s][tj * 4 + r];
        }
#pragma unroll
        for (int r = 0; r < 4; ++r)
#pragma unroll
            for (int c = 0; c < 4; ++c) {
                aq[r][c] += qd[r] * qe[c];
                ak[r][c] += kd[r] * ke[c];
            }
    }
    float* Gp = G + (size_t)bh * 4096;
#pragma unroll
    for (int r = 0; r < 4; ++r)
#pragma unroll
        for (int c = 0; c < 4; ++c)
            atomicAdd(&Gp[(ti * 4 + r) * 64 + tj * 4 + c], aq[r][c] + ak[r][c]);
    if (t < 128) {
        int which = t >> 6, d = t & 63;
        float s0 = 0.0f;
        if (which == 0) { for (int s = 0; s < 64; ++s) s0 += qt[s][d]; }
        else            { for (int s = 0; s < 64; ++s) s0 += ktl[s][d]; }
        atomicAdd(&musum[((size_t)which * 64 + bh) * 64 + d], s0);
    }
}

// ---------------------------------------------------------------------------
// per-bh 64x64 Jacobi eig: 512 threads, fp32 rotations, IN-PLACE A/V.
// W2 aliases G (A staged to LDS first).
// ---------------------------------------------------------------------------
__global__ __launch_bounds__(512)
void jacobi_eig(const float* __restrict__ G, const float* __restrict__ musum,
                float* __restrict__ W2, float* __restrict__ Dval)
{
    __shared__ float A[64][65];
    __shared__ float V[64][65];
    __shared__ float ca[64], sb[64];
    __shared__ float lam[64];
    __shared__ float muq[64], muk[64];
    int bh = blockIdx.x, t = threadIdx.x;
    const float invS = 1.0f / 1024.0f;
    if (t < 64) {
        muq[t] = musum[(size_t)bh * 64 + t] * invS;
        muk[t] = musum[4096 + (size_t)bh * 64 + t] * invS;
    }
    __syncthreads();
    const float* Gb = G + (size_t)bh * 4096;
#pragma unroll
    for (int r = 0; r < 8; ++r) {
        int idx = t + r * 512;
        int i = idx >> 6, j = idx & 63;
        A[i][j] = Gb[idx] * invS + muq[i] * muk[j] + muk[i] * muq[j];
        V[i][j] = (i == j) ? 1.0f : 0.0f;
    }
    __syncthreads();
    for (int sweep = 0; sweep < NSWEEP; ++sweep) {
        for (int m = 1; m < 64; ++m) {
            if (t < 64) {
                int q = t ^ m;
                if (t < q) {
                    float app = A[t][t], aqq = A[q][q], apq = A[t][q];
                    float c = 1.0f, s = 0.0f;
                    if (fabsf(apq) > 1e-28f) {
                        float tau = (aqq - app) / (2.0f * apq);
                        float tt = (tau >= 0.0f ? 1.0f : -1.0f)
                                 / (fabsf(tau) + sqrtf(1.0f + tau * tau));
                        float cd = 1.0f / sqrtf(1.0f + tt * tt);
                        c = cd; s = tt * cd;
                    }
                    ca[t] = c; sb[t] = -s;
                    ca[q] = c; sb[q] = s;
                }
            }
            __syncthreads();
            int hb = 31 - __builtin_clz((unsigned)m);
            int lowmask = (1 << hb) - 1;
            // A: 1024 quads, 2 per thread, in place (disjoint ownership)
#pragma unroll
            for (int r = 0; r < 2; ++r) {
                int idx = t + r * 512;
                int ki = idx >> 5, kj = idx & 31;
                int i1 = ((ki & ~lowmask) << 1) | (ki & lowmask);
                int i2 = i1 ^ m;
                int j1 = ((kj & ~lowmask) << 1) | (kj & lowmask);
                int j2 = j1 ^ m;
                float a11 = A[i1][j1], a12 = A[i1][j2];
                float a21 = A[i2][j1], a22 = A[i2][j2];
                float ci = ca[i1], si = sb[i1], ci2 = ca[i2], si2 = sb[i2];
                float cj = ca[j1], sj = sb[j1], cj2 = ca[j2], sj2 = sb[j2];
                float t11 = ci * a11 + si * a21, t12 = ci * a12 + si * a22;
                float t21 = ci2 * a21 + si2 * a11, t22 = ci2 * a22 + si2 * a12;
                A[i1][j1] = cj * t11 + sj * t12;
                A[i1][j2] = cj2 * t12 + sj2 * t11;
                A[i2][j1] = cj * t21 + sj * t22;
                A[i2][j2] = cj2 * t22 + sj2 * t21;
            }
            // V: 2048 pair-elements, 4 per thread, in place
#pragma unroll
            for (int r = 0; r < 4; ++r) {
                int idx = t + r * 512;
                int i = idx >> 5, kj = idx & 31;
                int j1 = ((kj & ~lowmask) << 1) | (kj & lowmask);
                int j2 = j1 ^ m;
                float v1 = V[i][j1], v2 = V[i][j2];
                V[i][j1] = ca[j1] * v1 + sb[j1] * v2;
                V[i][j2] = ca[j2] * v2 + sb[j2] * v1;
            }
            __syncthreads();
        }
    }
    if (t < 64) lam[t] = A[t][t];
    __syncthreads();
    if (t < 64) {
        int j = t;
        float lj = lam[j];
        int rank = 0;
        for (int k2 = 0; k2 < 64; ++k2) {
            float lk = lam[k2];
            rank += (lk > lj) || (lk == lj && k2 < j);
        }
        float tl = 2.0f * lj + 1.0f;
        float om = (3.0f + 2.0f * lj + sqrtf(tl * tl + 8.0f * lj)) * 0.25f;
        float cfac = sqrtf(om);
        float best = -1.0f; int bd = 0;
        for (int d = 0; d < 64; ++d) {
            float av = fabsf(V[d][j]);
            if (av > best) { best = av; bd = d; }
        }
        if (V[bd][j] < 0.0f) cfac = -cfac;
        for (int d = 0; d < 64; ++d)
            W2[((size_t)bh * 64 + d) * 64 + rank] = cfac * V[d][j];
        ca[j] = logf(om);
    }
    __syncthreads();
    if (t == 0) {
        float ssum = 0.0f;
        for (int j = 0; j < 64; ++j) ssum += ca[j];
        Dval[bh] = expf(0.25f * ssum);
    }
}

// ---------------------------------------------------------------------------
// feature map IN PLACE, all 64 bh (grid 64 x 16 x 2); overflow -> inf -> 0
// ---------------------------------------------------------------------------
__global__ __launch_bounds__(64)
void features_k(bf16* __restrict__ qb, bf16* __restrict__ kb,
                const float* __restrict__ W2g, const float* __restrict__ Dv,
                const float* __restrict__ hw)
{
    __shared__ float Wsh[64][64];
    __shared__ float hD[64];
    int bh = blockIdx.x, st = blockIdx.y, qk = blockIdx.z;
    int t = threadIdx.x;
    const float* W2b = W2g + (size_t)bh * 4096;
#pragma unroll
    for (int r = 0; r < 16; ++r)
        ((float4*)Wsh)[t + r * 64] = ((const float4*)W2b)[t + r * 64];
    hD[t] = hw[t] + Dv[t];
    bf16* buf = qk ? kb : qb;
    int row = st * 64 + t;
    bf16* rowp = buf + ((size_t)bh * 1024 + row) * 64;
    float q[64];
#pragma unroll
    for (int c = 0; c < 8; ++c) {
        v8s v = *(const v8s*)&rowp[c * 8];
#pragma unroll
        for (int i = 0; i < 8; ++i) q[c * 8 + i] = bf2f(v[i]);
    }
    __syncthreads();
    float x[64];
#pragma unroll
    for (int e = 0; e < 64; ++e) x[e] = hD[e];
    for (int d = 0; d < 64; ++d) {
        float qd = q[d];
        const float4* wrow = (const float4*)&Wsh[d][0];
#pragma unroll
        for (int e4 = 0; e4 < 16; ++e4) {
            float4 wv = wrow[e4];
            x[e4 * 4 + 0] += qd * wv.x;
            x[e4 * 4 + 1] += qd * wv.y;
            x[e4 * 4 + 2] += qd * wv.z;
            x[e4 * 4 + 3] += qd * wv.w;
        }
    }
    float te[64];
#pragma unroll
    for (int e = 0; e < 64; ++e) te[e] = expf(x[e]);
    float r8[8];
#pragma unroll
    for (int i = 0; i < 8; ++i) r8[i] = te[i] * te[i];
#pragma unroll
    for (int k = 1; k < 8; ++k)
#pragma unroll
        for (int i = 0; i < 8; ++i) r8[i] += te[k * 8 + i] * te[k * 8 + i];
    float s2 = ((r8[0] + r8[1]) + (r8[2] + r8[3])) + ((r8[4] + r8[5]) + (r8[6] + r8[7]));
    float inv = 1.0f / sqrtf(s2);     // inf -> 0 (np semantics)
#pragma unroll
    for (int e2 = 0; e2 < 32; ++e2) {
        __hip_bfloat162 pr;
        pr.x = __float2bfloat16(te[2 * e2] * inv);
        pr.y = __float2bfloat16(te[2 * e2 + 1] * inv);
        *(__hip_bfloat162*)&rowp[2 * e2] = pr;
    }
}

// ---------------------------------------------------------------------------
// flash attention, all 64 bh (grid 64 x 16); V slot chosen by bh>>4;
// ctx -> bf16 global [bh][s][d]
// ---------------------------------------------------------------------------
__global__ __launch_bounds__(256)
void flash_attn(const bf16* __restrict__ qn, const bf16* __restrict__ kn,
                const bf16* __restrict__ v0, const bf16* __restrict__ v1,
                const bf16* __restrict__ v2, const bf16* __restrict__ v3,
                bf16* __restrict__ ctx)
{
    __shared__ bf16 kt_s[64][72];
    __shared__ bf16 vt_s[64][72];
    __shared__ bf16 p_s[4][16][72];
    int bh = blockIdx.x, qt = blockIdx.y;
    int t = threadIdx.x, lane = t & 63, w = t >> 6;
    int quad = lane >> 4, l15 = lane & 15;
    int b = bh >> 4, hl = bh & 15;
    const bf16* vv = ((b == 0) ? v0 : (b == 1) ? v1 : (b == 2) ? v2 : v3)
                   + ((size_t)hl << 16);   // head offset 1024*64

    int qrow = qt * 64 + w * 16 + l15;
    const bf16* qptr = qn + ((size_t)bh * 1024 + qrow) * 64;
    v8s aq0 = *(const v8s*)&qptr[quad * 8];
    v8s aq1 = *(const v8s*)&qptr[32 + quad * 8];

    v4f zz = {0.f, 0.f, 0.f, 0.f};
    v4f ctxa[4];
#pragma unroll
    for (int dj = 0; dj < 4; ++dj) ctxa[dj] = zz;
    float mrun[4], lrun[4];
#pragma unroll
    for (int r = 0; r < 4; ++r) { mrun[r] = -__builtin_inff(); lrun[r] = 0.0f; }

    for (int kt = 0; kt < 16; ++kt) {
        __syncthreads();
#pragma unroll
        for (int r2 = 0; r2 < 2; ++r2) {
            int idx = t + r2 * 256;
            int row = idx >> 3, c8 = (idx & 7) * 8;
            *(float4*)&kt_s[row][c8] =
                *(const float4*)&kn[((size_t)bh * 1024 + kt * 64 + row) * 64 + c8];
            v8s vchunk = *(const v8s*)&vv[((size_t)(kt * 64 + row)) * 64 + c8];
#pragma unroll
            for (int i = 0; i < 8; ++i)
                ((short*)vt_s)[(c8 + i) * 72 + row] = vchunk[i];
        }
        __syncthreads();
        v4f sa[4];
#pragma unroll
        for (int j = 0; j < 4; ++j) {
            v8s bk0 = *(v8s*)&kt_s[j * 16 + l15][quad * 8];
            v8s bk1 = *(v8s*)&kt_s[j * 16 + l15][32 + quad * 8];
            v4f z = zz;
            z = __builtin_amdgcn_mfma_f32_16x16x32_bf16(aq0, bk0, z, 0, 0, 0);
            sa[j] = __builtin_amdgcn_mfma_f32_16x16x32_bf16(aq1, bk1, z, 0, 0, 0);
        }
        float pv[4][4];
        float alpha[4];
#pragma unroll
        for (int r = 0; r < 4; ++r) {
            float mx = fmaxf(fmaxf(sa[0][r], sa[1][r]), fmaxf(sa[2][r], sa[3][r]));
#pragma unroll
            for (int off = 1; off < 16; off <<= 1) mx = fmaxf(mx, __shfl_xor(mx, off, 64));
            float mnew = fmaxf(mrun[r], mx);
            alpha[r] = __expf(mrun[r] - mnew);
            float ps = 0.0f;
#pragma unroll
            for (int j = 0; j < 4; ++j) {
                float pe = __expf(sa[j][r] - mnew);
                pv[j][r] = pe; ps += pe;
            }
#pragma unroll
            for (int off = 1; off < 16; off <<= 1) ps += __shfl_xor(ps, off, 64);
            mrun[r] = mnew;
            lrun[r] = lrun[r] * alpha[r] + ps;
        }
#pragma unroll
        for (int j = 0; j < 4; ++j)
#pragma unroll
            for (int r = 0; r < 4; ++r)
                p_s[w][quad * 4 + r][j * 16 + l15] = __float2bfloat16(pv[j][r]);
#pragma unroll
        for (int dj = 0; dj < 4; ++dj)
#pragma unroll
            for (int r = 0; r < 4; ++r) ctxa[dj][r] *= alpha[r];
        __syncthreads();
        v8s ap0 = *(v8s*)&p_s[w][l15][quad * 8];
        v8s ap1 = *(v8s*)&p_s[w][l15][32 + quad * 8];
#pragma unroll
        for (int dj = 0; dj < 4; ++dj) {
            v8s bv0 = *(v8s*)&vt_s[dj * 16 + l15][quad * 8];
            v8s bv1 = *(v8s*)&vt_s[dj * 16 + l15][32 + quad * 8];
            ctxa[dj] = __builtin_amdgcn_mfma_f32_16x16x32_bf16(ap0, bv0, ctxa[dj], 0, 0, 0);
            ctxa[dj] = __builtin_amdgcn_mfma_f32_16x16x32_bf16(ap1, bv1, ctxa[dj], 0, 0, 0);
        }
    }
#pragma unroll
    for (int dj = 0; dj < 4; ++dj)
#pragma unroll
        for (int r = 0; r < 4; ++r) {
            int srow = qt * 64 + w * 16 + quad * 4 + r;
            int d = dj * 16 + l15;
            float val = ctxa[dj][r] / lrun[r];
            ctx[((size_t)bh * 1024 + srow) * 64 + d] = __float2bfloat16(val);
        }
}

// ---------------------------------------------------------------------------
extern "C" void kernel_launch(void* const* d_in, const int* in_sizes, int n_in,
                              void* d_out, int out_size, void* d_ws, size_t ws_size,
                              hipStream_t stream)
{
    const size_t OUT_N = 4194304;
    long mx = 0; int ih = -1;
    for (int i = 0; i < n_in; ++i)
        if ((long)in_sizes[i] > mx) { mx = in_sizes[i]; ih = i; }
    long szW = mx / 4, szR = mx / 1024, szB = mx / 4096;
    int wI[4], rI[2], bI[4], nW = 0, nR = 0, nB = 0;
    bool bad = (n_in != 11) || (mx % 4096 != 0);
    if (!bad) {
        for (int i = 0; i < n_in; ++i) {
            if (i == ih) continue;
            long s = in_sizes[i];
            if (s == szW && nW < 4) wI[nW++] = i;
            else if (s == szR && nR < 2) rI[nR++] = i;
            else if (s == szB && nB < 4) bI[nB++] = i;
            else bad = true;
        }
        if (nW != 4 || nR != 2 || nB != 4) bad = true;
    }
    if (bad) {
        diag_f32<<<256, 256, 0, stream>>>((float*)d_out, OUT_N, 333.0f);
        return;
    }
    const float *Wq, *Wk, *Wv, *Wo, *bq, *bk, *bv, *bo, *rm, *on;
    float *WqS, *WkS;
    if (ih == 8 && wI[0] == 0 && wI[1] == 1 && wI[2] == 2 && wI[3] == 3) {
        Wk = (const float*)d_in[wI[0]]; Wo = (const float*)d_in[wI[1]];
        Wq = (const float*)d_in[wI[2]]; Wv = (const float*)d_in[wI[3]];
        bk = (const float*)d_in[bI[0]]; bo = (const float*)d_in[bI[1]];
        bq = (const float*)d_in[bI[2]]; bv = (const float*)d_in[bI[3]];
        on = (const float*)d_in[rI[0]]; rm = (const float*)d_in[rI[1]];
        WqS = (float*)d_in[wI[2]]; WkS = (float*)d_in[wI[0]];
    } else {
        Wq = (const float*)d_in[wI[0]]; Wk = (const float*)d_in[wI[1]];
        Wv = (const float*)d_in[wI[2]]; Wo = (const float*)d_in[wI[3]];
        bq = (const float*)d_in[bI[0]]; bk = (const float*)d_in[bI[1]];
        bv = (const float*)d_in[bI[2]]; bo = (const float*)d_in[bI[3]];
        rm = (const float*)d_in[rI[0]]; on = (const float*)d_in[rI[1]];
        WqS = (float*)d_in[wI[0]]; WkS = (float*)d_in[wI[1]];
    }
    const float* hs = (const float*)d_in[ih];
    float* outF = (float*)d_out;

    bf16* Qf = (bf16*)d_out;
    bf16* Kf = (bf16*)((char*)d_out + (8u << 20));
    float* G     = WqS;
    float* musum = WqS + 262144;
    float* hw    = WqS + 262144 + 16384;
    float* Dval  = WqS + 262144 + 16384 + 1024;
    bf16* V0 = (bf16*)WkS;              bf16* V1 = (bf16*)WkS + 1048576;
    bf16* V2 = (bf16*)WqS;              bf16* V3 = (bf16*)WqS + 1048576;
    bf16* Ctx = (bf16*)d_in[ih];        // hs dead after V-GEMM (last hs read)

    const float scale = 0.125f;
    gemm_nt<1><<<dim3(32, 8), 256, 0, stream>>>(hs, Wq, bq, scale, Qf,
                                                nullptr, nullptr, nullptr, nullptr);
    gemm_nt<1><<<dim3(32, 8), 256, 0, stream>>>(hs, Wk, bk, scale, Kf,
                                                nullptr, nullptr, nullptr, nullptr);
    hipMemsetAsync(G, 0, 1u << 20, stream);
    hipMemsetAsync(musum, 0, 32768, stream);
    half_omega_k<<<1, 64, 0, stream>>>(rm, on, hw);
    gram_stats<<<dim3(64, 16), 256, 0, stream>>>(Qf, Kf, G, musum);
    jacobi_eig<<<64, 512, 0, stream>>>(G, musum, G, Dval);
    features_k<<<dim3(64, 16, 2), 64, 0, stream>>>(Qf, Kf, G, Dval, hw);
    gemm_nt<2><<<dim3(32, 8), 256, 0, stream>>>(hs, Wv, bv, 1.0f, V0, V1, V2, V3, nullptr);
    flash_attn<<<dim3(64, 16), 256, 0, stream>>>(Qf, Kf, V0, V1, V2, V3, Ctx);
    gemm_nt<3><<<dim3(32, 8), 256, 0, stream>>>(Ctx, Wo, bo, 1.0f,
                                                nullptr, nullptr, nullptr, nullptr, outF);
}